// Round 10
// baseline (33.920 us; speedup 1.0000x reference)
//
#include <hip/hip_runtime.h>
#include <math.h>

#define N_CG   50000
#define APC    13
#define FEAT   128
#define DEG    16
#define VOCAB  100
#define TPAD   16              // padded row stride of T (floats) -> 64B rows
#define ROWS_PER_BLK 16        // table: rows per block
#define CG_PER_BLK 16          // recon: cgs per task
#define TASKS_PER_BLK 4        // recon: tasks per block (amortize setup)
#define NTASK_RECON (N_CG / CG_PER_BLK)                    // 3125
#define RECON_BLKS ((NTASK_RECON + TASKS_PER_BLK - 1) / TASKS_PER_BLK)  // 782
#define PBLK   (VOCAB / 2)     // 50 GEMM blocks
#define PACKB  ((N_CG + 255) / 256)

// Kernel 1 (R3-exact): role A (blocks [0,50)): P = (z!=0 ? emb[z]:0) @ W_msg.
//                      role B (blocks [50,246)): xyz4[i]={x,y,z,bitcast(cg_z)}.
__global__ void p_pack_kernel(const float* __restrict__ emb,
                              const float* __restrict__ Wmsg,
                              const float* __restrict__ xyz,
                              const int*   __restrict__ cg_z,
                              float*  __restrict__ P,
                              float4* __restrict__ xyz4) {
    int b = blockIdx.x, t = threadIdx.x;
    if (b < PBLK) {                        // role A: P GEMM (once, 1.6M MAC)
        int z = b * 2 + (t >> 7);          // wave-uniform z
        int f = t & 127;
        float acc = 0.f;
        if (z != 0) {
            #pragma unroll 8
            for (int k = 0; k < FEAT; ++k)
                acc += emb[z * FEAT + k] * Wmsg[k * FEAT + f];
        }
        P[z * FEAT + f] = acc;
        return;
    }
    int i = (b - PBLK) * 256 + t;          // role B: pack
    if (i < N_CG)
        xyz4[i] = make_float4(xyz[3*i], xyz[3*i+1], xyz[3*i+2],
                              __int_as_float(cg_z[i]));
}

// Kernel 2 (R3-exact): T[row][c] = silu(P[zi]+P[zj]) @ W_vec, stride TPAD.
__global__ void table_kernel(const float* __restrict__ P,
                             const float* __restrict__ Wvec,
                             float* __restrict__ T) {
    __shared__ float hs[ROWS_PER_BLK][FEAT + 1];
    int t = threadIdx.x;
    int row0 = blockIdx.x * ROWS_PER_BLK;
    #pragma unroll
    for (int i = 0; i < (ROWS_PER_BLK * FEAT) / 256; ++i) {
        int v = t + i * 256;
        int r = v >> 7, f = v & 127;
        int row = row0 + r;
        int zi = row / VOCAB, zj = row % VOCAB;
        float h = P[zi * FEAT + f] + P[zj * FEAT + f];
        hs[r][f] = h / (1.f + expf(-h));   // silu
    }
    __syncthreads();
    if (t < ROWS_PER_BLK * APC) {
        int r = t / APC, c = t % APC;
        float s = 0.f;
        #pragma unroll 8
        for (int f = 0; f < FEAT; ++f)
            s += hs[r][f] * Wvec[f * APC + c];
        T[(size_t)(row0 + r) * TPAD + c] = s;
    }
}

// Kernel 3: recon, 4 tasks per block (task loop amortizes block setup/ramp;
// inner structure identical to the measured R3/R8 version).
__global__ void recon_kernel(const float4* __restrict__ xyz4,
                             const int*    __restrict__ nbr,
                             const int*    __restrict__ ca_idx,
                             const float*  __restrict__ T,
                             float* __restrict__ out) {
    __shared__ float4 eu[CG_PER_BLK][DEG + 1];     // padded: conflict-free
    __shared__ float4 xis[CG_PER_BLK];
    __shared__ int    cas[CG_PER_BLK];
    __shared__ float  obuf[CG_PER_BLK * APC * 3];  // 624 floats

    int t = threadIdx.x;
    int task0 = blockIdx.x * TASKS_PER_BLK;

    #pragma unroll 1
    for (int it = 0; it < TASKS_PER_BLK; ++it) {
        int task = task0 + it;
        if (task >= NTASK_RECON) break;
        int cg0 = task * CG_PER_BLK;

        {   // phase 1: one edge per thread
            int g = t >> 4, k = t & 15;
            int cg = cg0 + g;
            int e  = cg * DEG + k;             // src = repeat(arange, DEG)
            int2 ed = ((const int2*)nbr)[e];   // {src, dst} one 8B load
            int j = ed.y;
            float4 pj = xyz4[j];
            float4 pi = xyz4[cg];
            if (k == 0) xis[g] = pi;
            if (k == 1) cas[g] = ca_idx[cg];
            float dx = pj.x - pi.x, dy = pj.y - pi.y, dz = pj.z - pi.z;
            float inv = 1.f / (sqrtf(dx*dx + dy*dy + dz*dz) + 1e-8f);
            int row = __float_as_int(pi.w) * VOCAB + __float_as_int(pj.w);
            eu[g][k] = make_float4(dx*inv, dy*inv, dz*inv, __int_as_float(row));
        }
        __syncthreads();

        if (t < CG_PER_BLK * APC) {            // phase 2
            int g = t / APC, c = t % APC;
            float4 u[DEG];
            #pragma unroll
            for (int k = 0; k < DEG; ++k) u[k] = eu[g][k];   // LDS -> regs
            float w[DEG];
            #pragma unroll
            for (int k = 0; k < DEG; ++k)                    // 16 indep gathers
                w[k] = T[(size_t)__float_as_int(u[k].w) * TPAD + c];
            float a0 = 0.f, a1 = 0.f, a2 = 0.f;
            #pragma unroll
            for (int k = 0; k < DEG; ++k) {
                a0 += w[k] * u[k].x; a1 += w[k] * u[k].y; a2 += w[k] * u[k].z;
            }
            int cg = cg0 + g;
            if (c == cas[g] - cg * APC) { a0 = 0.f; a1 = 0.f; a2 = 0.f; }
            float4 xi = xis[g];
            obuf[t * 3 + 0] = a0 + xi.x;
            obuf[t * 3 + 1] = a1 + xi.y;
            obuf[t * 3 + 2] = a2 + xi.z;
        }
        __syncthreads();

        if (t < (CG_PER_BLK * APC * 3) / 4) {  // 156 float4, contiguous 2496B
            float4* ov = (float4*)(out + (size_t)task * (CG_PER_BLK * APC * 3));
            ov[t] = ((const float4*)obuf)[t];
        }
        __syncthreads();                       // protect eu/obuf for next task
    }
}

extern "C" void kernel_launch(void* const* d_in, const int* in_sizes, int n_in,
                              void* d_out, int out_size, void* d_ws, size_t ws_size,
                              hipStream_t stream) {
    const float* cg_xyz  = (const float*)d_in[0];
    const float* emb     = (const float*)d_in[1];
    const float* W_msg   = (const float*)d_in[2];
    const float* W_vec   = (const float*)d_in[3];
    const int*   cg_z    = (const int*)d_in[4];
    const int*   nbr     = (const int*)d_in[5];
    const int*   ca_idx  = (const int*)d_in[7];
    float* out = (float*)d_out;

    float*  T    = (float*)d_ws;                                        // 640 KB
    float4* xyz4 = (float4*)((char*)d_ws + (size_t)VOCAB*VOCAB*TPAD*4); // 800 KB
    float*  P    = (float*)((char*)xyz4 + (size_t)N_CG * 16);           // 51.2 KB

    p_pack_kernel<<<PBLK + PACKB, 256, 0, stream>>>(
        emb, W_msg, cg_xyz, cg_z, P, xyz4);
    table_kernel<<<(VOCAB * VOCAB) / ROWS_PER_BLK, 256, 0, stream>>>(
        P, W_vec, T);
    recon_kernel<<<RECON_BLKS, 256, 0, stream>>>(
        xyz4, nbr, ca_idx, T, out);
}

// Round 11
// 31.504 us; speedup vs baseline: 1.0767x; 1.0767x over previous
//
#include <hip/hip_runtime.h>
#include <math.h>

#define N_CG   50000
#define APC    13
#define FEAT   128
#define DEG    16
#define VOCAB  100
#define TPAD   16              // padded row stride of T (floats) -> 64B rows
#define ROWS_PER_BLK 16        // table: rows per block
#define CG_PER_BLK 16          // recon: cgs per block
#define PBLK   (VOCAB / 2)     // 50 GEMM blocks (2 z-rows per 256-thread block)
#define PACKB  ((N_CG + 255) / 256)

// Kernel 1: role A (blocks [0,50)): P = (z!=0 ? emb[z]:0) @ W_msg (once).
//           role B (blocks [50,246)): xyz4[i]={x,y,z,bitcast(cg_z)}.
__global__ void p_pack_kernel(const float* __restrict__ emb,
                              const float* __restrict__ Wmsg,
                              const float* __restrict__ xyz,
                              const int*   __restrict__ cg_z,
                              float*  __restrict__ P,
                              float4* __restrict__ xyz4) {
    int b = blockIdx.x, t = threadIdx.x;
    if (b < PBLK) {                        // role A: P GEMM (1.6M MAC total)
        int z = b * 2 + (t >> 7);          // wave-uniform z
        int f = t & 127;
        float acc = 0.f;
        if (z != 0) {
            #pragma unroll 8
            for (int k = 0; k < FEAT; ++k)
                acc += emb[z * FEAT + k] * Wmsg[k * FEAT + f];
        }
        P[z * FEAT + f] = acc;
        return;
    }
    int i = (b - PBLK) * 256 + t;          // role B: pack
    if (i < N_CG)
        xyz4[i] = make_float4(xyz[3*i], xyz[3*i+1], xyz[3*i+2],
                              __int_as_float(cg_z[i]));
}

// Kernel 2: T[row][c] = silu(P[zi]+P[zj]) @ W_vec, row = zi*VOCAB+zj,
// padded stride TPAD (64B rows -> 13 channel-gathers hit one line).
__global__ void table_kernel(const float* __restrict__ P,
                             const float* __restrict__ Wvec,
                             float* __restrict__ T) {
    __shared__ float hs[ROWS_PER_BLK][FEAT + 1];
    int t = threadIdx.x;
    int row0 = blockIdx.x * ROWS_PER_BLK;
    #pragma unroll
    for (int i = 0; i < (ROWS_PER_BLK * FEAT) / 256; ++i) {
        int v = t + i * 256;
        int r = v >> 7, f = v & 127;
        int row = row0 + r;
        int zi = row / VOCAB, zj = row % VOCAB;
        float h = P[zi * FEAT + f] + P[zj * FEAT + f];
        hs[r][f] = h / (1.f + expf(-h));   // silu
    }
    __syncthreads();
    if (t < ROWS_PER_BLK * APC) {
        int r = t / APC, c = t % APC;
        float s = 0.f;
        #pragma unroll 8
        for (int f = 0; f < FEAT; ++f)
            s += hs[r][f] * Wvec[f * APC + c];
        T[(size_t)(row0 + r) * TPAD + c] = s;
    }
}

// Kernel 3: fused segment-sum + reconstruction (R8's measured-best form).
// Phase 1: 256 edges/block; one int2 + two float4 gathers per edge; unit*inv
//   and T-row id packed into LDS float4.
// Phase 2: (cg,channel) threads: 16 LDS records -> regs, 16 independent
//   T-gathers (vmcnt-batched), FMA reduce; output staged in LDS and written
//   as 156 aligned float4 (contiguous 2496B per block).
__global__ void recon_kernel(const float4* __restrict__ xyz4,
                             const int*    __restrict__ nbr,
                             const int*    __restrict__ ca_idx,
                             const float*  __restrict__ T,
                             float* __restrict__ out) {
    __shared__ float4 eu[CG_PER_BLK][DEG + 1];     // padded: conflict-free
    __shared__ float4 xis[CG_PER_BLK];
    __shared__ int    cas[CG_PER_BLK];
    __shared__ float  obuf[CG_PER_BLK * APC * 3];  // 624 floats

    int t = threadIdx.x;
    int cg0 = blockIdx.x * CG_PER_BLK;

    {   // phase 1: one edge per thread
        int g = t >> 4, k = t & 15;
        int cg = cg0 + g;
        int e  = cg * DEG + k;             // src = repeat(arange(N_CG), DEG)
        int2 ed = ((const int2*)nbr)[e];   // {src, dst} one 8B load
        int j = ed.y;
        float4 pj = xyz4[j];
        float4 pi = xyz4[cg];
        if (k == 0) xis[g] = pi;
        if (k == 1) cas[g] = ca_idx[cg];
        float dx = pj.x - pi.x, dy = pj.y - pi.y, dz = pj.z - pi.z;
        float inv = 1.f / (sqrtf(dx*dx + dy*dy + dz*dz) + 1e-8f);
        int row = __float_as_int(pi.w) * VOCAB + __float_as_int(pj.w);
        eu[g][k] = make_float4(dx*inv, dy*inv, dz*inv, __int_as_float(row));
    }
    __syncthreads();

    if (t < CG_PER_BLK * APC) {            // phase 2
        int g = t / APC, c = t % APC;
        float4 u[DEG];
        #pragma unroll
        for (int k = 0; k < DEG; ++k) u[k] = eu[g][k];   // LDS -> regs, batched
        float w[DEG];
        #pragma unroll
        for (int k = 0; k < DEG; ++k)                    // 16 independent gathers
            w[k] = T[(size_t)__float_as_int(u[k].w) * TPAD + c];
        float a0 = 0.f, a1 = 0.f, a2 = 0.f;
        #pragma unroll
        for (int k = 0; k < DEG; ++k) {
            a0 += w[k] * u[k].x; a1 += w[k] * u[k].y; a2 += w[k] * u[k].z;
        }
        int cg = cg0 + g;
        if (c == cas[g] - cg * APC) { a0 = 0.f; a1 = 0.f; a2 = 0.f; }  // ca atom
        float4 xi = xis[g];
        obuf[t * 3 + 0] = a0 + xi.x;
        obuf[t * 3 + 1] = a1 + xi.y;
        obuf[t * 3 + 2] = a2 + xi.z;
    }
    __syncthreads();

    if (t < (CG_PER_BLK * APC * 3) / 4) {  // 156 float4, contiguous 2496B
        float4* ov = (float4*)(out + (size_t)blockIdx.x * (CG_PER_BLK * APC * 3));
        ov[t] = ((const float4*)obuf)[t];
    }
}

extern "C" void kernel_launch(void* const* d_in, const int* in_sizes, int n_in,
                              void* d_out, int out_size, void* d_ws, size_t ws_size,
                              hipStream_t stream) {
    const float* cg_xyz  = (const float*)d_in[0];
    const float* emb     = (const float*)d_in[1];
    const float* W_msg   = (const float*)d_in[2];
    const float* W_vec   = (const float*)d_in[3];
    const int*   cg_z    = (const int*)d_in[4];
    const int*   nbr     = (const int*)d_in[5];
    const int*   ca_idx  = (const int*)d_in[7];
    float* out = (float*)d_out;

    float*  T    = (float*)d_ws;                                        // 640 KB
    float4* xyz4 = (float4*)((char*)d_ws + (size_t)VOCAB*VOCAB*TPAD*4); // 800 KB
    float*  P    = (float*)((char*)xyz4 + (size_t)N_CG * 16);           // 51.2 KB

    p_pack_kernel<<<PBLK + PACKB, 256, 0, stream>>>(
        emb, W_msg, cg_xyz, cg_z, P, xyz4);
    table_kernel<<<(VOCAB * VOCAB) / ROWS_PER_BLK, 256, 0, stream>>>(
        P, W_vec, T);
    recon_kernel<<<N_CG / CG_PER_BLK, 256, 0, stream>>>(
        xyz4, nbr, ca_idx, T, out);
}